// Round 4
// baseline (732.845 us; speedup 1.0000x reference)
//
#include <hip/hip_runtime.h>

#define DIMV 768
#define BATCH 16
#define SEQ 1024
#define LN_EPS 1e-5f

typedef __attribute__((ext_vector_type(8))) short bf16x8;   // 8 bf16 = 4 VGPRs
typedef __attribute__((ext_vector_type(4))) float f32x4;
typedef unsigned short ushort_t;

__device__ __forceinline__ unsigned short f2bf(float f) {
    unsigned u = __float_as_uint(f);
    u = (u + 0x7FFFu + ((u >> 16) & 1u)) >> 16;
    return (unsigned short)u;
}

// ---------------------------------------------------------------------------
// bf16 MFMA NT GEMM, ring-4 LDS pipeline, DEPTH-2 prefetch:
//   C[m,n] = scale*sum_k A[m,k]*B[n,k] + bias
// A: bf16 row-major [M, lda]; B: bf16 row-major [N, ldb] (B^T input).
// 128x128 tile, BK=32, 256 threads = 4 waves (2x2), 4x4 MFMA frags/wave.
//
// Round-3 finding: with depth-1 prefetch the per-block-iter wall time was
// ~1500 cyc vs ~310 cyc of MFMA content (MfmaUtil 18%, bank conflicts 0,
// HBM 14%) -> the vmcnt wait on loads issued only one iteration ago is the
// critical path (T3/T4). Fix: ring-4 slots, issue tile k+2 each iter, wait
// vmcnt(8) so TWO tiles stay in flight across barriers. LDS 64 KB -> 2
// blocks/CU (was 3), but load slack doubles.
// Ring-4 safety (same invariant as ring-3/depth-1): slot (k+2)&3 was last
// read at iter k-2; those reads are consumed (lgkm-waited before MFMA)
// before each wave reaches barrier(k-1), which precedes the iter-k issue.
// Tail iters issue dummy loads of the last tile (L2-hot) to keep the vmcnt
// count uniform.
//
// LDS chunk swizzle [round 2, verified: SQ_LDS_BANK_CONFLICT 9.4M -> 0]:
// LDS dest linear (global_load_lds requirement); global source chunk
// pre-swizzled q ^ ((r>>1)&3); frag reads XOR the same term.
//
// XCD swizzles (hardware round-robins linear block id over 8 XCDs):
//  - Z>1: remap so XCD == batch (mod 8)     [round 0: worked]
//  - Z==1: chunked nl=(lid%8)*(nwg/8)+lid/8 [round 1: worked]
//
// mode: 0 = f32 out; 1 = bf16 out;
//       4 = fused KV epilogue producing branch-stacked attention operands:
//           bh = m>>10 (0..2Cb), half = bh>=Cb (A/B branch), b = bh - half*Cb
//           n < 768 : K  -> Kb2 [b][half*1024 + s][n]          (bf16)
//           n >= 768: V^T-> Vt2 [b][n-768][half*1024 + s]      (bf16)
// ---------------------------------------------------------------------------
__global__ __launch_bounds__(256) void gemm_bf16_nt(
    const ushort_t* __restrict__ A, const ushort_t* __restrict__ B,
    const float* __restrict__ bias, const float* __restrict__ bias2,
    void* __restrict__ Cout, void* __restrict__ Cout2,
    int K, int lda, int ldb, int ldc, float scale, int mode,
    long long sAz, long long sBz, long long sCz, int CbArg)
{
    int bx = blockIdx.x, by = blockIdx.y, bz = blockIdx.z;
    {
        const unsigned Z  = gridDim.z;
        const unsigned nx = gridDim.x, ny = gridDim.y;
        if (Z > 1) {
            const unsigned nxy = nx * ny;
            const unsigned lid = ((unsigned)bz * ny + (unsigned)by) * nx + (unsigned)bx;
            unsigned r;
            if ((Z & 7u) == 0u) {           // XCD c runs batch c, then c+8, ...
                const unsigned c  = lid & 7u;
                const unsigned rp = lid >> 3;
                bz = (int)(c + 8u * (rp / nxy));
                r  = rp % nxy;
            } else {                        // generic bijective fallback
                bz = (int)(lid % Z);
                r  = lid / Z;
            }
            bx = (int)(r % nx);
            by = (int)(r / nx);
        } else {
            const unsigned nwg = nx * ny;
            if ((nwg & 7u) == 0u) {         // chunked: XCD c owns contiguous y-range
                const unsigned lid = (unsigned)by * nx + (unsigned)bx;
                const unsigned nl  = (lid & 7u) * (nwg >> 3) + (lid >> 3);
                bx = (int)(nl % nx);
                by = (int)(nl / nx);
            }
        }
    }

    A += (long long)bz * sAz;
    B += (long long)bz * sBz;
    float*    Cf  = (float*)Cout    + ((mode == 0) ? (long long)bz * sCz : 0);
    ushort_t* Ch  = (ushort_t*)Cout + ((mode == 1) ? (long long)bz * sCz : 0);
    ushort_t* Ch2 = (ushort_t*)Cout2;

    __shared__ ushort_t As[4][128 * 32];   // 4 x 8 KB
    __shared__ ushort_t Bs[4][128 * 32];   // 4 x 8 KB  (64 KB total)

    const int t    = threadIdx.x;       // 0..255
    const int wave = t >> 6;
    const int lane = t & 63;
    const int quad = lane >> 4;         // 0..3
    const int lr   = lane & 15;         // 0..15
    const int wy   = wave >> 1;         // 0/1: m-half
    const int wx   = wave & 1;          // 0/1: n-half

    const int m0 = by * 128;
    const int n0 = bx * 128;

    const ushort_t* Abase = A + (long long)m0 * lda;
    const ushort_t* Bbase = B + (long long)n0 * ldb;

    auto issue = [&](int k0, int slot) {
        #pragma unroll
        for (int i = 0; i < 2; ++i) {
            const int idx = t + 256 * i;          // 0..511: 128 rows x 4 chunks
            const int r   = idx >> 2;
            const int q   = idx & 3;              // LDS chunk slot
            const int c   = (q ^ ((r >> 1) & 3)) * 8;  // swizzled global chunk
            __builtin_amdgcn_global_load_lds(
                (const __attribute__((address_space(1))) unsigned int*)(Abase + (long long)r * lda + k0 + c),
                (__attribute__((address_space(3))) unsigned int*)&As[slot][idx * 8], 16, 0, 0);
            __builtin_amdgcn_global_load_lds(
                (const __attribute__((address_space(1))) unsigned int*)(Bbase + (long long)r * ldb + k0 + c),
                (__attribute__((address_space(3))) unsigned int*)&Bs[slot][idx * 8], 16, 0, 0);
        }
    };

    // Swizzled frag-read offsets (loop-invariant): row's global chunk `quad`
    // lives at LDS slot quad ^ ((row>>1)&3).
    int offA[4], offB[4];
    #pragma unroll
    for (int i = 0; i < 4; ++i) {
        const int rowA = wy * 64 + i * 16 + lr;
        offA[i] = rowA * 32 + ((quad ^ ((rowA >> 1) & 3)) * 8);
        const int rowB = wx * 64 + i * 16 + lr;
        offB[i] = rowB * 32 + ((quad ^ ((rowB >> 1) & 3)) * 8);
    }

    f32x4 acc[4][4] = {};

    const int NK = K >> 5;                 // always >= 24 here
    issue(0, 0);
    issue(32, 1);
    for (int ki = 0; ki < NK; ++ki) {
        const int k2 = (ki + 2 < NK) ? (ki + 2) << 5 : (NK - 1) << 5;  // dummy = last tile (L2-hot)
        issue(k2, (ki + 2) & 3);
        asm volatile("s_waitcnt vmcnt(8)" ::: "memory");   // tile-k done; k+1,k+2 in flight
        asm volatile("s_barrier" ::: "memory");            // no vmcnt(0) drain

        const ushort_t* as = &As[ki & 3][0];
        const ushort_t* bs = &Bs[ki & 3][0];
        bf16x8 af[4], bfr[4];
        #pragma unroll
        for (int i = 0; i < 4; ++i) af[i]  = *(const bf16x8*)&as[offA[i]];
        #pragma unroll
        for (int j = 0; j < 4; ++j) bfr[j] = *(const bf16x8*)&bs[offB[j]];

        #pragma unroll
        for (int i = 0; i < 4; ++i)
            #pragma unroll
            for (int j = 0; j < 4; ++j)
                acc[i][j] = __builtin_amdgcn_mfma_f32_16x16x32_bf16(
                    af[i], bfr[j], acc[i][j], 0, 0, 0);
    }

    // epilogue: D row(m) = quad*4 + reg, col(n) = lane&15  [m89-verified]
    #pragma unroll
    for (int j = 0; j < 4; ++j) {
        const int n = n0 + wx * 64 + j * 16 + lr;
        float bv;
        if (mode == 4) bv = (n < DIMV) ? bias[n] : bias2[n - DIMV];
        else           bv = bias ? bias[n] : 0.0f;
        #pragma unroll
        for (int i = 0; i < 4; ++i) {
            #pragma unroll
            for (int r = 0; r < 4; ++r) {
                const int m = m0 + wy * 64 + i * 16 + quad * 4 + r;
                const float val = acc[i][j][r] * scale + bv;
                if (mode == 0) {
                    Cf[(long long)m * ldc + n] = val;
                } else if (mode == 1) {
                    Ch[(long long)m * ldc + n] = f2bf(val);
                } else {                      // mode 4: fused KV, branch-stacked
                    const int bh = m >> 10, s = m & 1023;
                    const int hf = (bh >= CbArg) ? 1 : 0;
                    const int b  = bh - (hf ? CbArg : 0);
                    if (n < DIMV) {           // K: Kb2[b][hf*1024 + s][n]
                        Ch[(long long)b * (2 * SEQ * DIMV) + (long long)(hf * SEQ + s) * DIMV + n] = f2bf(val);
                    } else {                  // V^T: Vt2[b][n-768][hf*1024 + s]
                        Ch2[(long long)b * (2 * SEQ * DIMV) + (long long)(n - DIMV) * (2 * SEQ) + hf * SEQ + s] = f2bf(val);
                    }
                }
            }
        }
    }
}

// ---------------------------------------------------------------------------
// f32 -> bf16 conversion, 4 elems/thread, count divisible by 1024
// ---------------------------------------------------------------------------
__global__ __launch_bounds__(256) void f32_to_bf16(
    const float* __restrict__ in, ushort_t* __restrict__ out)
{
    const long long i = ((long long)blockIdx.x * 256 + threadIdx.x) * 4;
    float4 v = *reinterpret_cast<const float4*>(in + i);
    ushort4 o;
    o.x = f2bf(v.x); o.y = f2bf(v.y); o.z = f2bf(v.z); o.w = f2bf(v.w);
    *reinterpret_cast<ushort4*>(out + i) = o;
}

// ---------------------------------------------------------------------------
// Dual in-place row softmax over a [2048] f32 row holding two independent
// 1024-logit halves (branch A = cols 0..1023, branch B = 1024..2047).
// Threads 0..127 own half A (8 f32 each), 128..255 own half B. The row is
// overwritten with 2048 contiguous bf16 probs (bf16 index == f32 index), so
// the PV GEMM reads rows of 2048 bf16 at pitch 4096 ushorts.
// All reads land in registers before the first __syncthreads (compiler
// emits vmcnt wait before red[] store), writes happen after the last one ->
// race-free, same argument as the round-0 kernel.
// ---------------------------------------------------------------------------
__global__ __launch_bounds__(256) void softmax2_inplace(float* __restrict__ S)
{
    float* s = S + (long long)blockIdx.x * (2 * SEQ);
    const int t  = threadIdx.x;
    const int hf = t >> 7;            // 0 = branch A, 1 = branch B
    const int tt = t & 127;
    const int base = hf * SEQ + tt * 8;
    __shared__ float red[256];

    float4 v0 = *reinterpret_cast<const float4*>(&s[base]);
    float4 v1 = *reinterpret_cast<const float4*>(&s[base + 4]);
    float mx = fmaxf(fmaxf(fmaxf(v0.x, v0.y), fmaxf(v0.z, v0.w)),
                     fmaxf(fmaxf(v1.x, v1.y), fmaxf(v1.z, v1.w)));
    red[t] = mx;
    __syncthreads();
    for (int st = 64; st > 0; st >>= 1) {
        if (tt < st) red[t] = fmaxf(red[t], red[t + st]);
        __syncthreads();
    }
    mx = red[hf << 7];
    __syncthreads();

    v0.x = __expf(v0.x - mx); v0.y = __expf(v0.y - mx);
    v0.z = __expf(v0.z - mx); v0.w = __expf(v0.w - mx);
    v1.x = __expf(v1.x - mx); v1.y = __expf(v1.y - mx);
    v1.z = __expf(v1.z - mx); v1.w = __expf(v1.w - mx);
    red[t] = (v0.x + v0.y + v0.z + v0.w) + (v1.x + v1.y + v1.z + v1.w);
    __syncthreads();
    for (int st = 64; st > 0; st >>= 1) {
        if (tt < st) red[t] += red[t + st];
        __syncthreads();
    }
    const float inv = 1.0f / red[hf << 7];

    ushort4 o0, o1;
    o0.x = f2bf(v0.x * inv); o0.y = f2bf(v0.y * inv);
    o0.z = f2bf(v0.z * inv); o0.w = f2bf(v0.w * inv);
    o1.x = f2bf(v1.x * inv); o1.y = f2bf(v1.y * inv);
    o1.z = f2bf(v1.z * inv); o1.w = f2bf(v1.w * inv);
    *reinterpret_cast<ushort4*>((ushort_t*)s + base)     = o0;
    *reinterpret_cast<ushort4*>((ushort_t*)s + base + 4) = o1;
}

// ---------------------------------------------------------------------------
// h = LayerNorm(ACC + xC) * gamma + beta -> bf16. One block per row (768).
// ---------------------------------------------------------------------------
__global__ __launch_bounds__(256) void add_layernorm(
    const float* __restrict__ ACC, const float* __restrict__ xC,
    const float* __restrict__ gamma, const float* __restrict__ beta,
    ushort_t* __restrict__ H)
{
    const long long row = blockIdx.x;
    const float* a = ACC + row * DIMV;
    const float* x = xC  + row * DIMV;
    ushort_t*    h = H   + row * DIMV;
    const int t = threadIdx.x;

    __shared__ float r1[256];
    __shared__ float r2[256];

    float vals[3];
    float s = 0.f, ss = 0.f;
    #pragma unroll
    for (int i = 0; i < 3; ++i) {
        const int j = t + i * 256;
        float v = a[j] + x[j];
        vals[i] = v;
        s += v; ss += v * v;
    }
    r1[t] = s; r2[t] = ss;
    __syncthreads();
    for (int st = 128; st > 0; st >>= 1) {
        if (t < st) { r1[t] += r1[t + st]; r2[t] += r2[t + st]; }
        __syncthreads();
    }
    const float mu  = r1[0] * (1.0f / DIMV);
    const float var = r2[0] * (1.0f / DIMV) - mu * mu;
    const float inv = rsqrtf(var + LN_EPS);

    #pragma unroll
    for (int i = 0; i < 3; ++i) {
        const int j = t + i * 256;
        h[j] = f2bf((vals[i] - mu) * inv * gamma[j] + beta[j]);
    }
}

// ---------------------------------------------------------------------------
// Launch — chunked over batches; footprint adapts to ws_size.
// Persistent: bf16 weights Wqb | Wkvb (=[Wk;Wv], 1536x768) | Wfcb (4.72 MB).
//
// Branch-fused attention (round 3 -> 4): K and V^T are stored BRANCH-STACKED
// per batch (Kb2 [b][2048][768], Vt2 [b][768][2048]) so that
//   - ONE score GEMM computes S_AB[b] = Q[b] @ [K_A;K_B]^T   (N = 2048)
//   - ONE dual softmax normalizes both halves of each 2048-row
//   - ONE PV GEMM with K = 2048 computes attn_A@V_A + attn_B@V_B as the
//     K-reduction (mode-3 ACC read-modify-write eliminated; 64 iters/block)
//
// Per-chunk layout with lifetime overlays (bytes per batch):
//   R1: xABb bf16 [2Cb][1024][768] == ACC f32 [Cb][1024][768]   (4*perB)
//   R2: Sf   f32  [Cb][1024][2048]; xCb bf16 overlay at start   (8*perP)
//   Qb  bf16 [Cb][1024][768]  (reused as h after scores)        (2*perB)
//   Kb  bf16 [Cb][2048][768]  branch-stacked K                  (4*perB)
//   Vtb bf16 [Cb][768][2048]  branch-stacked V^T                (4*perB)
// Total 14*perB + 8*perP = 19.4 MB/batch.
// ---------------------------------------------------------------------------
extern "C" void kernel_launch(void* const* d_in, const int* in_sizes, int n_in,
                              void* d_out, int out_size, void* d_ws, size_t ws_size,
                              hipStream_t stream)
{
    const float* xA    = (const float*)d_in[0];
    const float* xB    = (const float*)d_in[1];
    const float* xC    = (const float*)d_in[2];
    const float* Wq    = (const float*)d_in[3];
    const float* bq    = (const float*)d_in[4];
    const float* Wk    = (const float*)d_in[5];
    const float* bk    = (const float*)d_in[6];
    const float* Wv    = (const float*)d_in[7];
    const float* bv    = (const float*)d_in[8];
    const float* gamma = (const float*)d_in[9];
    const float* beta  = (const float*)d_in[10];
    const float* Wfc   = (const float*)d_in[11];
    const float* bfc   = (const float*)d_in[12];
    float* out = (float*)d_out;

    const long long eW   = (long long)DIMV * DIMV;   // 589,824
    const long long perB = (long long)SEQ * DIMV;    // 786,432
    const long long perP = (long long)SEQ * SEQ;     // 1,048,576

    const long long wBytes        = 4 * eW * 2;                  // 4.72 MB
    const long long perBatchBytes = 14 * perB + 8 * perP;        // 19,398,656

    long long Cmax = ((long long)ws_size - wBytes) / perBatchBytes;
    if (Cmax > BATCH) Cmax = BATCH;
    if (Cmax < 1)     Cmax = 1;
    const int nChunks = (int)((BATCH + Cmax - 1) / Cmax);
    const int CbStd   = (BATCH + nChunks - 1) / nChunks;   // balanced chunks

    // persistent weight region
    char* cur = (char*)d_ws;
    ushort_t* Wqb  = (ushort_t*)cur; cur += eW * 2;
    ushort_t* Wkvb = (ushort_t*)cur; cur += 2 * eW * 2;    // [Wk; Wv] 1536x768
    ushort_t* Wfcb = (ushort_t*)cur; cur += eW * 2;
    char* chunkBase = cur;

    const float scale = 0.03608439182435161f;  // 1/sqrt(768)

    // 0) convert weights to bf16 (once)
    f32_to_bf16<<<(int)(eW / 1024), 256, 0, stream>>>(Wq,  Wqb);
    f32_to_bf16<<<(int)(eW / 1024), 256, 0, stream>>>(Wk,  Wkvb);
    f32_to_bf16<<<(int)(eW / 1024), 256, 0, stream>>>(Wv,  Wkvb + eW);
    f32_to_bf16<<<(int)(eW / 1024), 256, 0, stream>>>(Wfc, Wfcb);

    for (int b0 = 0; b0 < BATCH; b0 += CbStd) {
        const int Cb = (b0 + CbStd <= BATCH) ? CbStd : (BATCH - b0);
        const long long off = (long long)b0 * perB;

        // chunk workspace layout (see header comment for overlays)
        char* p = chunkBase;
        ushort_t* xABb = (ushort_t*)p;
        float*    ACC  = (float*)p;    p += (long long)Cb * 4 * perB;   // R1
        float*    Sf   = (float*)p;
        ushort_t* xCb  = (ushort_t*)p; p += (long long)Cb * 8 * perP;   // R2
        ushort_t* Qb   = (ushort_t*)p; p += (long long)Cb * 2 * perB;
        ushort_t* Kb   = (ushort_t*)p; p += (long long)Cb * 4 * perB;
        ushort_t* Vtb  = (ushort_t*)p; p += (long long)Cb * 4 * perB;

        dim3 gq  (DIMV / 128, Cb * (SEQ / 128), 1);           // M = Cb*1024
        dim3 gkv (2 * DIMV / 128, 2 * Cb * (SEQ / 128), 1);   // M = 2*Cb*1024, N = 1536
        dim3 gsc2(2 * SEQ / 128, SEQ / 128, Cb);              // N = 2048
        dim3 gpv (DIMV / 128, SEQ / 128, Cb);                 // K = 2048
        const int gcv = (int)((long long)Cb * perB / 1024);

        // 1) projections: Q from xC; fused K|V GEMM from stacked xA|xB,
        //    epilogue writes branch-stacked Kb2 / Vt2
        f32_to_bf16<<<gcv, 256, 0, stream>>>(xC + off, xCb);
        gemm_bf16_nt<<<gq, 256, 0, stream>>>(xCb, Wqb, bq, nullptr, Qb, nullptr,
            DIMV, DIMV, DIMV, DIMV, 1.f, 1, 0, 0, 0, 0);
        f32_to_bf16<<<gcv, 256, 0, stream>>>(xA + off, xABb);
        f32_to_bf16<<<gcv, 256, 0, stream>>>(xB + off, xABb + (long long)Cb * perB);
        gemm_bf16_nt<<<gkv, 256, 0, stream>>>(xABb, Wkvb, bk, bv, Kb, Vtb,
            DIMV, DIMV, DIMV, DIMV, 1.f, 4, 0, 0, 0, Cb);

        // 2) fused scores: S_AB = Q @ [K_A;K_B]^T  (one dispatch, N=2048)
        gemm_bf16_nt<<<gsc2, 256, 0, stream>>>(Qb, Kb, nullptr, nullptr, Sf, nullptr,
            DIMV, DIMV, DIMV, 2 * SEQ, scale, 0, perB, 2 * perB, 2 * perP, 0);

        // 3) dual softmax in place: each 2048-row -> 2048 contiguous bf16 probs
        softmax2_inplace<<<Cb * SEQ, 256, 0, stream>>>(Sf);

        // 4) fused PV: ACC = [P_A|P_B] @ [V_A;V_B]  (K = 2048, no RMW)
        gemm_bf16_nt<<<gpv, 256, 0, stream>>>((const ushort_t*)Sf, Vtb, nullptr, nullptr, ACC, nullptr,
            2 * SEQ, 4 * SEQ, 2 * SEQ, DIMV, 1.f, 0, 4 * perP, 2 * perB, perB, 0);

        // 5) h = LN(ACC + xC) -> bf16, into Qb (Q is dead now)
        add_layernorm<<<Cb * SEQ, 256, 0, stream>>>(ACC, xC + off, gamma, beta, Qb);

        // 6) out = h @ Wfc^T + bfc (f32 out)
        gemm_bf16_nt<<<gq, 256, 0, stream>>>(Qb, Wfcb, bfc, nullptr, out + off, nullptr,
            DIMV, DIMV, DIMV, DIMV, 1.f, 0, 0, 0, 0, 0);
    }
}

// Round 5
// 643.307 us; speedup vs baseline: 1.1392x; 1.1392x over previous
//
#include <hip/hip_runtime.h>

#define DIMV 768
#define BATCH 16
#define SEQ 1024
#define LN_EPS 1e-5f

typedef __attribute__((ext_vector_type(8))) short bf16x8;   // 8 bf16 = 4 VGPRs
typedef __attribute__((ext_vector_type(4))) float f32x4;
typedef unsigned short ushort_t;

__device__ __forceinline__ unsigned short f2bf(float f) {
    unsigned u = __float_as_uint(f);
    u = (u + 0x7FFFu + ((u >> 16) & 1u)) >> 16;
    return (unsigned short)u;
}

// ---------------------------------------------------------------------------
// bf16 MFMA NT GEMM, ring-3 LDS pipeline, depth-1 prefetch:
//   C[m,n] = scale*sum_k A[m,k]*B[n,k] + bias
// A: bf16 row-major [M, lda]; B: bf16 row-major [N, ldb] (B^T input).
// 128x128 tile, BK=32, 256 threads = 4 waves (2x2), 4x4 MFMA frags/wave.
//
// Pipeline history: depth-1 ring-3 (48 KB, 3 blocks/CU, Occ 27%) measured
// 427 TF on the KV shape. Round-4 depth-2 ring-4 (64 KB, 2 blocks/CU) was
// REFUTED: 379 TF, Occ 18.5%, MfmaUtil 15.3% -- latency hiding here comes
// from resident-block TLP, not pipeline depth. Reverted to ring-3.
// Ring-3 safety: slot written at iter k was last read at iter k-2; those
// reads precede barrier(k-1), which precedes the iter-k issue. Last iter
// issues a dummy wrap prefetch so the vmcnt count stays uniform.
//
// LDS chunk swizzle [verified: SQ_LDS_BANK_CONFLICT 9.4M -> 0]: LDS dest
// linear (global_load_lds requirement); global source chunk pre-swizzled
// q ^ ((r>>1)&3); frag reads XOR the same term.
//
// XCD swizzles (hardware round-robins linear block id over 8 XCDs):
//  - Z>1: remap so XCD == batch (mod 8)      [verified round 0/1]
//  - Z==1: chunked nl=(lid%8)*(nwg/8)+lid/8  [verified round 1]
//
// mode: 0 = f32 out; 1 = bf16 out;
//       4 = fused KV epilogue producing branch-stacked attention operands:
//           bh = m>>10 (0..2Cb), half = bh>=Cb (A/B branch), b = bh - half*Cb
//           n < 768 : K  -> Kb2 [b][half*1024 + s][n]          (bf16)
//           n >= 768: V^T-> Vt2 [b][n-768][half*1024 + s]      (bf16)
// ---------------------------------------------------------------------------
__global__ __launch_bounds__(256) void gemm_bf16_nt(
    const ushort_t* __restrict__ A, const ushort_t* __restrict__ B,
    const float* __restrict__ bias, const float* __restrict__ bias2,
    void* __restrict__ Cout, void* __restrict__ Cout2,
    int K, int lda, int ldb, int ldc, float scale, int mode,
    long long sAz, long long sBz, long long sCz, int CbArg)
{
    int bx = blockIdx.x, by = blockIdx.y, bz = blockIdx.z;
    {
        const unsigned Z  = gridDim.z;
        const unsigned nx = gridDim.x, ny = gridDim.y;
        if (Z > 1) {
            const unsigned nxy = nx * ny;
            const unsigned lid = ((unsigned)bz * ny + (unsigned)by) * nx + (unsigned)bx;
            unsigned r;
            if ((Z & 7u) == 0u) {           // XCD c runs batch c, then c+8, ...
                const unsigned c  = lid & 7u;
                const unsigned rp = lid >> 3;
                bz = (int)(c + 8u * (rp / nxy));
                r  = rp % nxy;
            } else {                        // generic bijective fallback
                bz = (int)(lid % Z);
                r  = lid / Z;
            }
            bx = (int)(r % nx);
            by = (int)(r / nx);
        } else {
            const unsigned nwg = nx * ny;
            if ((nwg & 7u) == 0u) {         // chunked: XCD c owns contiguous y-range
                const unsigned lid = (unsigned)by * nx + (unsigned)bx;
                const unsigned nl  = (lid & 7u) * (nwg >> 3) + (lid >> 3);
                bx = (int)(nl % nx);
                by = (int)(nl / nx);
            }
        }
    }

    A += (long long)bz * sAz;
    B += (long long)bz * sBz;
    float*    Cf  = (float*)Cout    + ((mode == 0) ? (long long)bz * sCz : 0);
    ushort_t* Ch  = (ushort_t*)Cout + ((mode == 1) ? (long long)bz * sCz : 0);
    ushort_t* Ch2 = (ushort_t*)Cout2;

    __shared__ ushort_t As[3][128 * 32];   // 3 x 8 KB
    __shared__ ushort_t Bs[3][128 * 32];   // 3 x 8 KB  (48 KB total)

    const int t    = threadIdx.x;       // 0..255
    const int wave = t >> 6;
    const int lane = t & 63;
    const int quad = lane >> 4;         // 0..3
    const int lr   = lane & 15;         // 0..15
    const int wy   = wave >> 1;         // 0/1: m-half
    const int wx   = wave & 1;          // 0/1: n-half

    const int m0 = by * 128;
    const int n0 = bx * 128;

    const ushort_t* Abase = A + (long long)m0 * lda;
    const ushort_t* Bbase = B + (long long)n0 * ldb;

    auto issue = [&](int k0, int slot) {
        #pragma unroll
        for (int i = 0; i < 2; ++i) {
            const int idx = t + 256 * i;          // 0..511: 128 rows x 4 chunks
            const int r   = idx >> 2;
            const int q   = idx & 3;              // LDS chunk slot
            const int c   = (q ^ ((r >> 1) & 3)) * 8;  // swizzled global chunk
            __builtin_amdgcn_global_load_lds(
                (const __attribute__((address_space(1))) unsigned int*)(Abase + (long long)r * lda + k0 + c),
                (__attribute__((address_space(3))) unsigned int*)&As[slot][idx * 8], 16, 0, 0);
            __builtin_amdgcn_global_load_lds(
                (const __attribute__((address_space(1))) unsigned int*)(Bbase + (long long)r * ldb + k0 + c),
                (__attribute__((address_space(3))) unsigned int*)&Bs[slot][idx * 8], 16, 0, 0);
        }
    };

    // Swizzled frag-read offsets (loop-invariant): row's global chunk `quad`
    // lives at LDS slot quad ^ ((row>>1)&3).
    int offA[4], offB[4];
    #pragma unroll
    for (int i = 0; i < 4; ++i) {
        const int rowA = wy * 64 + i * 16 + lr;
        offA[i] = rowA * 32 + ((quad ^ ((rowA >> 1) & 3)) * 8);
        const int rowB = wx * 64 + i * 16 + lr;
        offB[i] = rowB * 32 + ((quad ^ ((rowB >> 1) & 3)) * 8);
    }

    f32x4 acc[4][4] = {};

    const int NK = K >> 5;
    issue(0, 0);
    int cur = 0, nxt = 1;
    for (int ki = 0; ki < NK; ++ki) {
        const int kn = (ki + 1 < NK) ? (ki + 1) << 5 : 0;  // dummy wrap on last
        issue(kn, nxt);
        asm volatile("s_waitcnt vmcnt(4)" ::: "memory");   // tile-k loads done
        asm volatile("s_barrier" ::: "memory");            // no vmcnt(0) drain

        const ushort_t* as = &As[cur][0];
        const ushort_t* bs = &Bs[cur][0];
        bf16x8 af[4], bfr[4];
        #pragma unroll
        for (int i = 0; i < 4; ++i) af[i]  = *(const bf16x8*)&as[offA[i]];
        #pragma unroll
        for (int j = 0; j < 4; ++j) bfr[j] = *(const bf16x8*)&bs[offB[j]];

        #pragma unroll
        for (int i = 0; i < 4; ++i)
            #pragma unroll
            for (int j = 0; j < 4; ++j)
                acc[i][j] = __builtin_amdgcn_mfma_f32_16x16x32_bf16(
                    af[i], bfr[j], acc[i][j], 0, 0, 0);

        cur = nxt;
        nxt = (nxt == 2) ? 0 : nxt + 1;
    }

    // epilogue: D row(m) = quad*4 + reg, col(n) = lane&15  [m89-verified]
    #pragma unroll
    for (int j = 0; j < 4; ++j) {
        const int n = n0 + wx * 64 + j * 16 + lr;
        float bv;
        if (mode == 4) bv = (n < DIMV) ? bias[n] : bias2[n - DIMV];
        else           bv = bias ? bias[n] : 0.0f;
        #pragma unroll
        for (int i = 0; i < 4; ++i) {
            #pragma unroll
            for (int r = 0; r < 4; ++r) {
                const int m = m0 + wy * 64 + i * 16 + quad * 4 + r;
                const float val = acc[i][j][r] * scale + bv;
                if (mode == 0) {
                    Cf[(long long)m * ldc + n] = val;
                } else if (mode == 1) {
                    Ch[(long long)m * ldc + n] = f2bf(val);
                } else {                      // mode 4: fused KV, branch-stacked
                    const int bh = m >> 10, s = m & 1023;
                    const int hf = (bh >= CbArg) ? 1 : 0;
                    const int b  = bh - (hf ? CbArg : 0);
                    if (n < DIMV) {           // K: Kb2[b][hf*1024 + s][n]
                        Ch[(long long)b * (2 * SEQ * DIMV) + (long long)(hf * SEQ + s) * DIMV + n] = f2bf(val);
                    } else {                  // V^T: Vt2[b][n-768][hf*1024 + s]
                        Ch2[(long long)b * (2 * SEQ * DIMV) + (long long)(n - DIMV) * (2 * SEQ) + hf * SEQ + s] = f2bf(val);
                    }
                }
            }
        }
    }
}

// ---------------------------------------------------------------------------
// f32 -> bf16 conversion, 4 elems/thread, count divisible by 1024
// ---------------------------------------------------------------------------
__global__ __launch_bounds__(256) void f32_to_bf16(
    const float* __restrict__ in, ushort_t* __restrict__ out)
{
    const long long i = ((long long)blockIdx.x * 256 + threadIdx.x) * 4;
    float4 v = *reinterpret_cast<const float4*>(in + i);
    ushort4 o;
    o.x = f2bf(v.x); o.y = f2bf(v.y); o.z = f2bf(v.z); o.w = f2bf(v.w);
    *reinterpret_cast<ushort4*>(out + i) = o;
}

// ---------------------------------------------------------------------------
// Dual in-place row softmax over a [2048] f32 row holding two independent
// 1024-logit halves (branch A = cols 0..1023, branch B = 1024..2047).
// Threads 0..127 own half A (8 f32 each), 128..255 own half B. The row is
// overwritten with 2048 contiguous bf16 probs (bf16 index == f32 index), so
// the PV GEMM reads rows of 2048 bf16 at pitch 4096 ushorts.
// All reads land in registers before the first __syncthreads, writes happen
// after the last one -> race-free.  [verified round 4]
// ---------------------------------------------------------------------------
__global__ __launch_bounds__(256) void softmax2_inplace(float* __restrict__ S)
{
    float* s = S + (long long)blockIdx.x * (2 * SEQ);
    const int t  = threadIdx.x;
    const int hf = t >> 7;            // 0 = branch A, 1 = branch B
    const int tt = t & 127;
    const int base = hf * SEQ + tt * 8;
    __shared__ float red[256];

    float4 v0 = *reinterpret_cast<const float4*>(&s[base]);
    float4 v1 = *reinterpret_cast<const float4*>(&s[base + 4]);
    float mx = fmaxf(fmaxf(fmaxf(v0.x, v0.y), fmaxf(v0.z, v0.w)),
                     fmaxf(fmaxf(v1.x, v1.y), fmaxf(v1.z, v1.w)));
    red[t] = mx;
    __syncthreads();
    for (int st = 64; st > 0; st >>= 1) {
        if (tt < st) red[t] = fmaxf(red[t], red[t + st]);
        __syncthreads();
    }
    mx = red[hf << 7];
    __syncthreads();

    v0.x = __expf(v0.x - mx); v0.y = __expf(v0.y - mx);
    v0.z = __expf(v0.z - mx); v0.w = __expf(v0.w - mx);
    v1.x = __expf(v1.x - mx); v1.y = __expf(v1.y - mx);
    v1.z = __expf(v1.z - mx); v1.w = __expf(v1.w - mx);
    red[t] = (v0.x + v0.y + v0.z + v0.w) + (v1.x + v1.y + v1.z + v1.w);
    __syncthreads();
    for (int st = 64; st > 0; st >>= 1) {
        if (tt < st) red[t] += red[t + st];
        __syncthreads();
    }
    const float inv = 1.0f / red[hf << 7];

    ushort4 o0, o1;
    o0.x = f2bf(v0.x * inv); o0.y = f2bf(v0.y * inv);
    o0.z = f2bf(v0.z * inv); o0.w = f2bf(v0.w * inv);
    o1.x = f2bf(v1.x * inv); o1.y = f2bf(v1.y * inv);
    o1.z = f2bf(v1.z * inv); o1.w = f2bf(v1.w * inv);
    *reinterpret_cast<ushort4*>((ushort_t*)s + base)     = o0;
    *reinterpret_cast<ushort4*>((ushort_t*)s + base + 4) = o1;
}

// ---------------------------------------------------------------------------
// h = LayerNorm(ACC + xC) * gamma + beta -> bf16. One block per row (768).
// ---------------------------------------------------------------------------
__global__ __launch_bounds__(256) void add_layernorm(
    const float* __restrict__ ACC, const float* __restrict__ xC,
    const float* __restrict__ gamma, const float* __restrict__ beta,
    ushort_t* __restrict__ H)
{
    const long long row = blockIdx.x;
    const float* a = ACC + row * DIMV;
    const float* x = xC  + row * DIMV;
    ushort_t*    h = H   + row * DIMV;
    const int t = threadIdx.x;

    __shared__ float r1[256];
    __shared__ float r2[256];

    float vals[3];
    float s = 0.f, ss = 0.f;
    #pragma unroll
    for (int i = 0; i < 3; ++i) {
        const int j = t + i * 256;
        float v = a[j] + x[j];
        vals[i] = v;
        s += v; ss += v * v;
    }
    r1[t] = s; r2[t] = ss;
    __syncthreads();
    for (int st = 128; st > 0; st >>= 1) {
        if (t < st) { r1[t] += r1[t + st]; r2[t] += r2[t + st]; }
        __syncthreads();
    }
    const float mu  = r1[0] * (1.0f / DIMV);
    const float var = r2[0] * (1.0f / DIMV) - mu * mu;
    const float inv = rsqrtf(var + LN_EPS);

    #pragma unroll
    for (int i = 0; i < 3; ++i) {
        const int j = t + i * 256;
        h[j] = f2bf((vals[i] - mu) * inv * gamma[j] + beta[j]);
    }
}

// ---------------------------------------------------------------------------
// Launch. Persistent: bf16 weights Wqb | Wkvb (=[Wk;Wv]) | Wfcb (4.72 MB).
//
// Lifetime-overlay layout per chunk (restores single-chunk Cb=16 while
// keeping branch-fused attention; round-4 regression was 2-chunk split):
//   Region S (size max(8*perP*SC, 4*perB*Cb) bytes):
//     xCb bf16 [Cb][1024][768]   (dead after Q GEMM)
//     xABb bf16 [2Cb][1024][768] (written after Q GEMM, dead after KV GEMM)
//     Sf f32 [SC][1024][2048]    (written by score GEMM, after KV)
//   Qb   bf16 [Cb][1024][768]   (Q, reused as h after last score)
//   KbACC: Kb bf16 [Cb][2048][768] == ACC f32 [Cb][1024][768] (same size &
//     per-batch stride; Kb[b] dead after score(b), PV(b) writes ACC[b] over
//     it; with SC-batch sub-passes, pass-p PV only clobbers pass-p K)
//   Vtb  bf16 [Cb][768][2048]
// Footprint: 10*perB + max(8*perP*SC, 4*perB*Cb) bytes/chunk
//   (Cb=16, SC=8: 193 MB; SC grows to Cb if workspace allows).
//
// Attention is branch-fused per sub-pass of SC batches:
//   ONE score GEMM  S_AB = Q @ [K_A;K_B]^T      (N = 2048)
//   ONE dual softmax (in-place f32 -> bf16)
//   ONE PV GEMM  ACC = [P_A|P_B] @ [V_A;V_B]    (K = 2048, no RMW)
// ---------------------------------------------------------------------------
extern "C" void kernel_launch(void* const* d_in, const int* in_sizes, int n_in,
                              void* d_out, int out_size, void* d_ws, size_t ws_size,
                              hipStream_t stream)
{
    const float* xA    = (const float*)d_in[0];
    const float* xB    = (const float*)d_in[1];
    const float* xC    = (const float*)d_in[2];
    const float* Wq    = (const float*)d_in[3];
    const float* bq    = (const float*)d_in[4];
    const float* Wk    = (const float*)d_in[5];
    const float* bk    = (const float*)d_in[6];
    const float* Wv    = (const float*)d_in[7];
    const float* bv    = (const float*)d_in[8];
    const float* gamma = (const float*)d_in[9];
    const float* beta  = (const float*)d_in[10];
    const float* Wfc   = (const float*)d_in[11];
    const float* bfc   = (const float*)d_in[12];
    float* out = (float*)d_out;

    const long long eW   = (long long)DIMV * DIMV;   // 589,824
    const long long perB = (long long)SEQ * DIMV;    // 786,432 elems
    const long long perP = (long long)SEQ * SEQ;     // 1,048,576 elems

    const long long wBytes = 4 * eW * 2;             // 4.72 MB

    auto needBytes = [&](long long cb, long long sc) {
        const long long s = 8 * perP * sc;           // Sf f32 bytes
        const long long x = 4 * perB * cb;           // xABb bf16 bytes
        return (s > x ? s : x) + 10 * perB * cb;     // + Qb + KbACC + Vtb
    };

    // largest chunk size that fits (attention sub-pass capped at 8 for sizing)
    int CbFit = 1;
    for (int c = BATCH; c >= 1; --c) {
        const long long sc = c < 8 ? c : 8;
        if (wBytes + needBytes(c, sc) <= (long long)ws_size) { CbFit = c; break; }
    }
    const int nChunks = (BATCH + CbFit - 1) / CbFit;
    const int CbStd   = (BATCH + nChunks - 1) / nChunks;   // balanced chunks

    // persistent weight region
    char* cur = (char*)d_ws;
    ushort_t* Wqb  = (ushort_t*)cur; cur += eW * 2;
    ushort_t* Wkvb = (ushort_t*)cur; cur += 2 * eW * 2;    // [Wk; Wv] 1536x768
    ushort_t* Wfcb = (ushort_t*)cur; cur += eW * 2;
    char* chunkBase = cur;

    const float scale = 0.03608439182435161f;  // 1/sqrt(768)

    // 0) convert weights to bf16 (once)
    f32_to_bf16<<<(int)(eW / 1024), 256, 0, stream>>>(Wq,  Wqb);
    f32_to_bf16<<<(int)(eW / 1024), 256, 0, stream>>>(Wk,  Wkvb);
    f32_to_bf16<<<(int)(eW / 1024), 256, 0, stream>>>(Wv,  Wkvb + eW);
    f32_to_bf16<<<(int)(eW / 1024), 256, 0, stream>>>(Wfc, Wfcb);

    for (int b0 = 0; b0 < BATCH; b0 += CbStd) {
        const int Cb = (b0 + CbStd <= BATCH) ? CbStd : (BATCH - b0);
        const long long off = (long long)b0 * perB;

        // largest attention sub-pass that fits (prefer no split)
        int SC = Cb;
        while (SC > 1 && wBytes + needBytes(Cb, SC) > (long long)ws_size) --SC;

        const long long Sbytes =
            (8 * perP * (long long)SC > 4 * perB * (long long)Cb)
                ? 8 * perP * (long long)SC : 4 * perB * (long long)Cb;

        char* p = chunkBase;
        ushort_t* xCb  = (ushort_t*)p;                 // overlay 1 in region S
        ushort_t* xABb = (ushort_t*)p;                 // overlay 2 in region S
        float*    Sf   = (float*)p;    p += Sbytes;    // overlay 3 in region S
        ushort_t* Qb   = (ushort_t*)p; p += 2 * perB * Cb;
        ushort_t* Kb   = (ushort_t*)p;
        float*    ACC  = (float*)p;    p += 4 * perB * Cb;   // ACC overlays Kb
        ushort_t* Vtb  = (ushort_t*)p; p += 4 * perB * Cb;

        dim3 gq  (DIMV / 128, Cb * (SEQ / 128), 1);           // M = Cb*1024
        dim3 gkv (2 * DIMV / 128, 2 * Cb * (SEQ / 128), 1);   // M = 2*Cb*1024, N = 1536
        const int gcv = (int)((long long)Cb * perB / 1024);

        // 1) projections: Q from xC; fused K|V GEMM from stacked xA|xB
        f32_to_bf16<<<gcv, 256, 0, stream>>>(xC + off, xCb);
        gemm_bf16_nt<<<gq, 256, 0, stream>>>(xCb, Wqb, bq, nullptr, Qb, nullptr,
            DIMV, DIMV, DIMV, DIMV, 1.f, 1, 0, 0, 0, 0);
        f32_to_bf16<<<gcv, 256, 0, stream>>>(xA + off, xABb);
        f32_to_bf16<<<gcv, 256, 0, stream>>>(xB + off, xABb + (long long)Cb * perB);
        gemm_bf16_nt<<<gkv, 256, 0, stream>>>(xABb, Wkvb, bk, bv, Kb, Vtb,
            DIMV, DIMV, DIMV, DIMV, 1.f, 4, 0, 0, 0, Cb);

        // 2) branch-fused attention, SC batches per sub-pass
        for (int s0 = 0; s0 < Cb; s0 += SC) {
            const int sc = (s0 + SC <= Cb) ? SC : (Cb - s0);
            dim3 gsc(2 * SEQ / 128, SEQ / 128, sc);           // N = 2048
            dim3 gpv(DIMV / 128, SEQ / 128, sc);              // K = 2048

            gemm_bf16_nt<<<gsc, 256, 0, stream>>>(
                Qb + (long long)s0 * perB, Kb + (long long)s0 * 2 * perB,
                nullptr, nullptr, Sf, nullptr,
                DIMV, DIMV, DIMV, 2 * SEQ, scale, 0, perB, 2 * perB, 2 * perP, 0);

            softmax2_inplace<<<sc * SEQ, 256, 0, stream>>>(Sf);

            gemm_bf16_nt<<<gpv, 256, 0, stream>>>(
                (const ushort_t*)Sf, Vtb + (long long)s0 * 2 * perB,
                nullptr, nullptr, ACC + (long long)s0 * perB, nullptr,
                2 * SEQ, 4 * SEQ, 2 * SEQ, DIMV, 1.f, 0, 4 * perP, 2 * perB, perB, 0);
        }

        // 3) h = LN(ACC + xC) -> bf16, into Qb (Q is dead now)
        add_layernorm<<<Cb * SEQ, 256, 0, stream>>>(ACC, xC + off, gamma, beta, Qb);

        // 4) out = h @ Wfc^T + bfc (f32 out)
        gemm_bf16_nt<<<gq, 256, 0, stream>>>(Qb, Wfcb, bfc, nullptr, out + off, nullptr,
            DIMV, DIMV, DIMV, DIMV, 1.f, 0, 0, 0, 0, 0);
    }
}

// Round 6
// 637.112 us; speedup vs baseline: 1.1503x; 1.0097x over previous
//
#include <hip/hip_runtime.h>

#define DIMV 768
#define BATCH 16
#define SEQ 1024
#define LN_EPS 1e-5f

typedef __attribute__((ext_vector_type(8))) short bf16x8;   // 8 bf16 = 4 VGPRs
typedef __attribute__((ext_vector_type(4))) float f32x4;
typedef unsigned short ushort_t;

__device__ __forceinline__ unsigned short f2bf(float f) {
    unsigned u = __float_as_uint(f);
    u = (u + 0x7FFFu + ((u >> 16) & 1u)) >> 16;
    return (unsigned short)u;
}

// ---------------------------------------------------------------------------
// Shared building blocks (verified rounds 0-5):
//  - ring-3 LDS pipeline, depth-1 prefetch, ONE raw s_barrier + counted
//    s_waitcnt vmcnt(4) per iter (no vmcnt(0) drain). Depth-2 was REFUTED
//    (round 4: occupancy loss > latency gain).
//  - LDS chunk swizzle q ^ ((r>>1)&3) on global SOURCE + frag-read XOR
//    (SQ_LDS_BANK_CONFLICT 9.4M -> 0, verified round 3).
//  - XCD swizzles: Z>1 -> XCD == batch (mod 8); Z==1 -> chunked contiguous
//    y-range per XCD (FETCH 165 MB -> 66 MB ~= compulsory, verified).
//
// Round-5 finding: EVERY 128^2-tile GEMM dispatch sits at 425-505 TF
// regardless of locality/conflicts/HBM -- the structure's small-K ceiling
// (matches guide's m102 shape curve). Fix = tile size: 256x256, 8 waves,
// 64 MFMA per wave-iter vs 16, same per-thread staging cost.
// ---------------------------------------------------------------------------

// ---------------------------------------------------------------------------
// 256x256 tile GEMM: 512 threads = 8 waves (2 m-halves x 4 n-quarters),
// per-wave 128x64 output = acc[8][4] f32x4. BK=32, ring-3 LDS (96 KB),
// 1 block/CU, 2 waves/SIMD.
// mode: 0 = f32 out; 1 = bf16 out;
//       4 = fused KV epilogue, branch-stacked attention operands:
//           bh = m>>10, half = bh>=CbArg, b = bh - half*CbArg
//           n < 768 : K  -> Cout [b][half*1024 + s][n]       (bf16)
//           n >= 768: V^T-> Cout2[b][n-768][half*1024 + s]   (bf16)
// ---------------------------------------------------------------------------
__global__ __launch_bounds__(512, 2) void gemm_bf16_nt_256(
    const ushort_t* __restrict__ A, const ushort_t* __restrict__ B,
    const float* __restrict__ bias, const float* __restrict__ bias2,
    void* __restrict__ Cout, void* __restrict__ Cout2,
    int K, int lda, int ldb, int ldc, float scale, int mode,
    long long sAz, long long sBz, long long sCz, int CbArg)
{
    int bx = blockIdx.x, by = blockIdx.y, bz = blockIdx.z;
    {
        const unsigned Z  = gridDim.z;
        const unsigned nx = gridDim.x, ny = gridDim.y;
        if (Z > 1) {
            const unsigned nxy = nx * ny;
            const unsigned lid = ((unsigned)bz * ny + (unsigned)by) * nx + (unsigned)bx;
            unsigned r;
            if ((Z & 7u) == 0u) {
                const unsigned c  = lid & 7u;
                const unsigned rp = lid >> 3;
                bz = (int)(c + 8u * (rp / nxy));
                r  = rp % nxy;
            } else {
                bz = (int)(lid % Z);
                r  = lid / Z;
            }
            bx = (int)(r % nx);
            by = (int)(r / nx);
        } else {
            const unsigned nwg = nx * ny;
            if ((nwg & 7u) == 0u) {
                const unsigned lid = (unsigned)by * nx + (unsigned)bx;
                const unsigned nl  = (lid & 7u) * (nwg >> 3) + (lid >> 3);
                bx = (int)(nl % nx);
                by = (int)(nl / nx);
            }
        }
    }

    A += (long long)bz * sAz;
    B += (long long)bz * sBz;
    float*    Cf  = (float*)Cout    + ((mode == 0) ? (long long)bz * sCz : 0);
    ushort_t* Ch  = (ushort_t*)Cout + ((mode == 1) ? (long long)bz * sCz : 0);
    ushort_t* Ch2 = (ushort_t*)Cout2;

    __shared__ ushort_t As[3][256 * 32];   // 3 x 16 KB
    __shared__ ushort_t Bs[3][256 * 32];   // 3 x 16 KB  (96 KB total)

    const int t    = threadIdx.x;       // 0..511
    const int wave = t >> 6;            // 0..7
    const int lane = t & 63;
    const int quad = lane >> 4;         // 0..3
    const int lr   = lane & 15;         // 0..15
    const int wy   = wave >> 2;         // 0/1: m-half (128 rows)
    const int wx   = wave & 3;          // 0..3: n-quarter (64 cols)

    const int m0 = by * 256;
    const int n0 = bx * 256;

    const ushort_t* Abase = A + (long long)m0 * lda;
    const ushort_t* Bbase = B + (long long)n0 * ldb;

    auto issue = [&](int k0, int slot) {
        #pragma unroll
        for (int i = 0; i < 2; ++i) {
            const int idx = t + 512 * i;          // 0..1023: 256 rows x 4 chunks
            const int r   = idx >> 2;
            const int q   = idx & 3;              // LDS chunk slot
            const int c   = (q ^ ((r >> 1) & 3)) * 8;  // swizzled global chunk
            __builtin_amdgcn_global_load_lds(
                (const __attribute__((address_space(1))) unsigned int*)(Abase + (long long)r * lda + k0 + c),
                (__attribute__((address_space(3))) unsigned int*)&As[slot][idx * 8], 16, 0, 0);
            __builtin_amdgcn_global_load_lds(
                (const __attribute__((address_space(1))) unsigned int*)(Bbase + (long long)r * ldb + k0 + c),
                (__attribute__((address_space(3))) unsigned int*)&Bs[slot][idx * 8], 16, 0, 0);
        }
    };

    int offA[8], offB[4];
    #pragma unroll
    for (int i = 0; i < 8; ++i) {
        const int rowA = wy * 128 + i * 16 + lr;
        offA[i] = rowA * 32 + ((quad ^ ((rowA >> 1) & 3)) * 8);
    }
    #pragma unroll
    for (int j = 0; j < 4; ++j) {
        const int rowB = wx * 64 + j * 16 + lr;
        offB[j] = rowB * 32 + ((quad ^ ((rowB >> 1) & 3)) * 8);
    }

    f32x4 acc[8][4] = {};

    const int NK = K >> 5;
    issue(0, 0);
    int cur = 0, nxt = 1;
    for (int ki = 0; ki < NK; ++ki) {
        const int kn = (ki + 1 < NK) ? (ki + 1) << 5 : 0;  // dummy wrap on last
        issue(kn, nxt);
        asm volatile("s_waitcnt vmcnt(4)" ::: "memory");   // tile-k loads done
        asm volatile("s_barrier" ::: "memory");            // no vmcnt(0) drain

        const ushort_t* as = &As[cur][0];
        const ushort_t* bs = &Bs[cur][0];
        bf16x8 af[8], bfr[4];
        #pragma unroll
        for (int i = 0; i < 8; ++i) af[i]  = *(const bf16x8*)&as[offA[i]];
        #pragma unroll
        for (int j = 0; j < 4; ++j) bfr[j] = *(const bf16x8*)&bs[offB[j]];

        #pragma unroll
        for (int i = 0; i < 8; ++i)
            #pragma unroll
            for (int j = 0; j < 4; ++j)
                acc[i][j] = __builtin_amdgcn_mfma_f32_16x16x32_bf16(
                    af[i], bfr[j], acc[i][j], 0, 0, 0);

        cur = nxt;
        nxt = (nxt == 2) ? 0 : nxt + 1;
    }

    // epilogue: D row(m) = quad*4 + reg, col(n) = lane&15  [m89-verified]
    #pragma unroll
    for (int j = 0; j < 4; ++j) {
        const int n = n0 + wx * 64 + j * 16 + lr;
        float bv;
        if (mode == 4) bv = (n < DIMV) ? bias[n] : bias2[n - DIMV];
        else           bv = bias ? bias[n] : 0.0f;
        #pragma unroll
        for (int i = 0; i < 8; ++i) {
            #pragma unroll
            for (int r = 0; r < 4; ++r) {
                const int m = m0 + wy * 128 + i * 16 + quad * 4 + r;
                const float val = acc[i][j][r] * scale + bv;
                if (mode == 0) {
                    Cf[(long long)m * ldc + n] = val;
                } else if (mode == 1) {
                    Ch[(long long)m * ldc + n] = f2bf(val);
                } else {                      // mode 4: fused KV, branch-stacked
                    const int bh = m >> 10, s = m & 1023;
                    const int hf = (bh >= CbArg) ? 1 : 0;
                    const int b  = bh - (hf ? CbArg : 0);
                    if (n < DIMV) {
                        Ch[(long long)b * (2 * SEQ * DIMV) + (long long)(hf * SEQ + s) * DIMV + n] = f2bf(val);
                    } else {
                        Ch2[(long long)b * (2 * SEQ * DIMV) + (long long)(n - DIMV) * (2 * SEQ) + hf * SEQ + s] = f2bf(val);
                    }
                }
            }
        }
    }
}

// ---------------------------------------------------------------------------
// 128x128 tile GEMM (verified rounds 0-5) — kept for PV, whose per-batch
// grid (N=768, M=1024) underfills the chip at 256^2 tiles.
// mode: 0 = f32 out only (PV usage).
// ---------------------------------------------------------------------------
__global__ __launch_bounds__(256) void gemm_bf16_nt(
    const ushort_t* __restrict__ A, const ushort_t* __restrict__ B,
    const float* __restrict__ bias, void* __restrict__ Cout,
    int K, int lda, int ldb, int ldc, float scale,
    long long sAz, long long sBz, long long sCz)
{
    int bx = blockIdx.x, by = blockIdx.y, bz = blockIdx.z;
    {
        const unsigned Z  = gridDim.z;
        const unsigned nx = gridDim.x, ny = gridDim.y;
        if (Z > 1) {
            const unsigned nxy = nx * ny;
            const unsigned lid = ((unsigned)bz * ny + (unsigned)by) * nx + (unsigned)bx;
            unsigned r;
            if ((Z & 7u) == 0u) {
                const unsigned c  = lid & 7u;
                const unsigned rp = lid >> 3;
                bz = (int)(c + 8u * (rp / nxy));
                r  = rp % nxy;
            } else {
                bz = (int)(lid % Z);
                r  = lid / Z;
            }
            bx = (int)(r % nx);
            by = (int)(r / nx);
        } else {
            const unsigned nwg = nx * ny;
            if ((nwg & 7u) == 0u) {
                const unsigned lid = (unsigned)by * nx + (unsigned)bx;
                const unsigned nl  = (lid & 7u) * (nwg >> 3) + (lid >> 3);
                bx = (int)(nl % nx);
                by = (int)(nl / nx);
            }
        }
    }

    A += (long long)bz * sAz;
    B += (long long)bz * sBz;
    float* Cf = (float*)Cout + (long long)bz * sCz;

    __shared__ ushort_t As[3][128 * 32];
    __shared__ ushort_t Bs[3][128 * 32];

    const int t    = threadIdx.x;
    const int wave = t >> 6;
    const int lane = t & 63;
    const int quad = lane >> 4;
    const int lr   = lane & 15;
    const int wy   = wave >> 1;
    const int wx   = wave & 1;

    const int m0 = by * 128;
    const int n0 = bx * 128;

    const ushort_t* Abase = A + (long long)m0 * lda;
    const ushort_t* Bbase = B + (long long)n0 * ldb;

    auto issue = [&](int k0, int slot) {
        #pragma unroll
        for (int i = 0; i < 2; ++i) {
            const int idx = t + 256 * i;
            const int r   = idx >> 2;
            const int q   = idx & 3;
            const int c   = (q ^ ((r >> 1) & 3)) * 8;
            __builtin_amdgcn_global_load_lds(
                (const __attribute__((address_space(1))) unsigned int*)(Abase + (long long)r * lda + k0 + c),
                (__attribute__((address_space(3))) unsigned int*)&As[slot][idx * 8], 16, 0, 0);
            __builtin_amdgcn_global_load_lds(
                (const __attribute__((address_space(1))) unsigned int*)(Bbase + (long long)r * ldb + k0 + c),
                (__attribute__((address_space(3))) unsigned int*)&Bs[slot][idx * 8], 16, 0, 0);
        }
    };

    int offA[4], offB[4];
    #pragma unroll
    for (int i = 0; i < 4; ++i) {
        const int rowA = wy * 64 + i * 16 + lr;
        offA[i] = rowA * 32 + ((quad ^ ((rowA >> 1) & 3)) * 8);
        const int rowB = wx * 64 + i * 16 + lr;
        offB[i] = rowB * 32 + ((quad ^ ((rowB >> 1) & 3)) * 8);
    }

    f32x4 acc[4][4] = {};

    const int NK = K >> 5;
    issue(0, 0);
    int cur = 0, nxt = 1;
    for (int ki = 0; ki < NK; ++ki) {
        const int kn = (ki + 1 < NK) ? (ki + 1) << 5 : 0;
        issue(kn, nxt);
        asm volatile("s_waitcnt vmcnt(4)" ::: "memory");
        asm volatile("s_barrier" ::: "memory");

        const ushort_t* as = &As[cur][0];
        const ushort_t* bs = &Bs[cur][0];
        bf16x8 af[4], bfr[4];
        #pragma unroll
        for (int i = 0; i < 4; ++i) af[i]  = *(const bf16x8*)&as[offA[i]];
        #pragma unroll
        for (int j = 0; j < 4; ++j) bfr[j] = *(const bf16x8*)&bs[offB[j]];

        #pragma unroll
        for (int i = 0; i < 4; ++i)
            #pragma unroll
            for (int j = 0; j < 4; ++j)
                acc[i][j] = __builtin_amdgcn_mfma_f32_16x16x32_bf16(
                    af[i], bfr[j], acc[i][j], 0, 0, 0);

        cur = nxt;
        nxt = (nxt == 2) ? 0 : nxt + 1;
    }

    #pragma unroll
    for (int j = 0; j < 4; ++j) {
        const int n = n0 + wx * 64 + j * 16 + lr;
        const float bv = bias ? bias[n] : 0.0f;
        #pragma unroll
        for (int i = 0; i < 4; ++i) {
            #pragma unroll
            for (int r = 0; r < 4; ++r) {
                const int m = m0 + wy * 64 + i * 16 + quad * 4 + r;
                Cf[(long long)m * ldc + n] = acc[i][j][r] * scale + bv;
            }
        }
    }
}

// ---------------------------------------------------------------------------
// f32 -> bf16 conversion, 4 elems/thread, count divisible by 1024
// ---------------------------------------------------------------------------
__global__ __launch_bounds__(256) void f32_to_bf16(
    const float* __restrict__ in, ushort_t* __restrict__ out)
{
    const long long i = ((long long)blockIdx.x * 256 + threadIdx.x) * 4;
    float4 v = *reinterpret_cast<const float4*>(in + i);
    ushort4 o;
    o.x = f2bf(v.x); o.y = f2bf(v.y); o.z = f2bf(v.z); o.w = f2bf(v.w);
    *reinterpret_cast<ushort4*>(out + i) = o;
}

// ---------------------------------------------------------------------------
// Dual in-place row softmax over a [2048] f32 row (two independent 1024
// halves). Row overwritten with 2048 contiguous bf16 probs. [verified r4]
// ---------------------------------------------------------------------------
__global__ __launch_bounds__(256) void softmax2_inplace(float* __restrict__ S)
{
    float* s = S + (long long)blockIdx.x * (2 * SEQ);
    const int t  = threadIdx.x;
    const int hf = t >> 7;
    const int tt = t & 127;
    const int base = hf * SEQ + tt * 8;
    __shared__ float red[256];

    float4 v0 = *reinterpret_cast<const float4*>(&s[base]);
    float4 v1 = *reinterpret_cast<const float4*>(&s[base + 4]);
    float mx = fmaxf(fmaxf(fmaxf(v0.x, v0.y), fmaxf(v0.z, v0.w)),
                     fmaxf(fmaxf(v1.x, v1.y), fmaxf(v1.z, v1.w)));
    red[t] = mx;
    __syncthreads();
    for (int st = 64; st > 0; st >>= 1) {
        if (tt < st) red[t] = fmaxf(red[t], red[t + st]);
        __syncthreads();
    }
    mx = red[hf << 7];
    __syncthreads();

    v0.x = __expf(v0.x - mx); v0.y = __expf(v0.y - mx);
    v0.z = __expf(v0.z - mx); v0.w = __expf(v0.w - mx);
    v1.x = __expf(v1.x - mx); v1.y = __expf(v1.y - mx);
    v1.z = __expf(v1.z - mx); v1.w = __expf(v1.w - mx);
    red[t] = (v0.x + v0.y + v0.z + v0.w) + (v1.x + v1.y + v1.z + v1.w);
    __syncthreads();
    for (int st = 64; st > 0; st >>= 1) {
        if (tt < st) red[t] += red[t + st];
        __syncthreads();
    }
    const float inv = 1.0f / red[hf << 7];

    ushort4 o0, o1;
    o0.x = f2bf(v0.x * inv); o0.y = f2bf(v0.y * inv);
    o0.z = f2bf(v0.z * inv); o0.w = f2bf(v0.w * inv);
    o1.x = f2bf(v1.x * inv); o1.y = f2bf(v1.y * inv);
    o1.z = f2bf(v1.z * inv); o1.w = f2bf(v1.w * inv);
    *reinterpret_cast<ushort4*>((ushort_t*)s + base)     = o0;
    *reinterpret_cast<ushort4*>((ushort_t*)s + base + 4) = o1;
}

// ---------------------------------------------------------------------------
// h = LayerNorm(ACC + xC) * gamma + beta -> bf16. One block per row (768).
// ---------------------------------------------------------------------------
__global__ __launch_bounds__(256) void add_layernorm(
    const float* __restrict__ ACC, const float* __restrict__ xC,
    const float* __restrict__ gamma, const float* __restrict__ beta,
    ushort_t* __restrict__ H)
{
    const long long row = blockIdx.x;
    const float* a = ACC + row * DIMV;
    const float* x = xC  + row * DIMV;
    ushort_t*    h = H   + row * DIMV;
    const int t = threadIdx.x;

    __shared__ float r1[256];
    __shared__ float r2[256];

    float vals[3];
    float s = 0.f, ss = 0.f;
    #pragma unroll
    for (int i = 0; i < 3; ++i) {
        const int j = t + i * 256;
        float v = a[j] + x[j];
        vals[i] = v;
        s += v; ss += v * v;
    }
    r1[t] = s; r2[t] = ss;
    __syncthreads();
    for (int st = 128; st > 0; st >>= 1) {
        if (t < st) { r1[t] += r1[t + st]; r2[t] += r2[t + st]; }
        __syncthreads();
    }
    const float mu  = r1[0] * (1.0f / DIMV);
    const float var = r2[0] * (1.0f / DIMV) - mu * mu;
    const float inv = rsqrtf(var + LN_EPS);

    #pragma unroll
    for (int i = 0; i < 3; ++i) {
        const int j = t + i * 256;
        h[j] = f2bf((vals[i] - mu) * inv * gamma[j] + beta[j]);
    }
}

// ---------------------------------------------------------------------------
// Launch. Persistent: bf16 weights Wqb | Wkvb (=[Wk;Wv]) | Wfcb (4.72 MB).
// Lifetime-overlay layout per chunk [verified round 5, single chunk Cb=16]:
//   Region S: xCb / xABb / Sf (sequential lifetimes)
//   Qb; KbACC (Kb overlaid by ACC per sub-pass); Vtb
// Attention branch-fused per SC-batch sub-pass:
//   score (N=2048) -> dual softmax -> PV (K=2048, no RMW).
// 256^2-tile GEMM for Q/KV/score/fc; 128^2 for PV.
// ---------------------------------------------------------------------------
extern "C" void kernel_launch(void* const* d_in, const int* in_sizes, int n_in,
                              void* d_out, int out_size, void* d_ws, size_t ws_size,
                              hipStream_t stream)
{
    const float* xA    = (const float*)d_in[0];
    const float* xB    = (const float*)d_in[1];
    const float* xC    = (const float*)d_in[2];
    const float* Wq    = (const float*)d_in[3];
    const float* bq    = (const float*)d_in[4];
    const float* Wk    = (const float*)d_in[5];
    const float* bk    = (const float*)d_in[6];
    const float* Wv    = (const float*)d_in[7];
    const float* bv    = (const float*)d_in[8];
    const float* gamma = (const float*)d_in[9];
    const float* beta  = (const float*)d_in[10];
    const float* Wfc   = (const float*)d_in[11];
    const float* bfc   = (const float*)d_in[12];
    float* out = (float*)d_out;

    const long long eW   = (long long)DIMV * DIMV;   // 589,824
    const long long perB = (long long)SEQ * DIMV;    // 786,432 elems
    const long long perP = (long long)SEQ * SEQ;     // 1,048,576 elems

    const long long wBytes = 4 * eW * 2;             // 4.72 MB

    auto needBytes = [&](long long cb, long long sc) {
        const long long s = 8 * perP * sc;           // Sf f32 bytes
        const long long x = 4 * perB * cb;           // xABb bf16 bytes
        return (s > x ? s : x) + 10 * perB * cb;     // + Qb + KbACC + Vtb
    };

    int CbFit = 1;
    for (int c = BATCH; c >= 1; --c) {
        const long long sc = c < 8 ? c : 8;
        if (wBytes + needBytes(c, sc) <= (long long)ws_size) { CbFit = c; break; }
    }
    const int nChunks = (BATCH + CbFit - 1) / CbFit;
    const int CbStd   = (BATCH + nChunks - 1) / nChunks;

    char* cur = (char*)d_ws;
    ushort_t* Wqb  = (ushort_t*)cur; cur += eW * 2;
    ushort_t* Wkvb = (ushort_t*)cur; cur += 2 * eW * 2;    // [Wk; Wv] 1536x768
    ushort_t* Wfcb = (ushort_t*)cur; cur += eW * 2;
    char* chunkBase = cur;

    const float scale = 0.03608439182435161f;  // 1/sqrt(768)

    f32_to_bf16<<<(int)(eW / 1024), 256, 0, stream>>>(Wq,  Wqb);
    f32_to_bf16<<<(int)(eW / 1024), 256, 0, stream>>>(Wk,  Wkvb);
    f32_to_bf16<<<(int)(eW / 1024), 256, 0, stream>>>(Wv,  Wkvb + eW);
    f32_to_bf16<<<(int)(eW / 1024), 256, 0, stream>>>(Wfc, Wfcb);

    for (int b0 = 0; b0 < BATCH; b0 += CbStd) {
        const int Cb = (b0 + CbStd <= BATCH) ? CbStd : (BATCH - b0);
        const long long off = (long long)b0 * perB;

        int SC = Cb;
        while (SC > 1 && wBytes + needBytes(Cb, SC) > (long long)ws_size) --SC;

        const long long Sbytes =
            (8 * perP * (long long)SC > 4 * perB * (long long)Cb)
                ? 8 * perP * (long long)SC : 4 * perB * (long long)Cb;

        char* p = chunkBase;
        ushort_t* xCb  = (ushort_t*)p;                 // overlay 1 in region S
        ushort_t* xABb = (ushort_t*)p;                 // overlay 2 in region S
        float*    Sf   = (float*)p;    p += Sbytes;    // overlay 3 in region S
        ushort_t* Qb   = (ushort_t*)p; p += 2 * perB * Cb;
        ushort_t* Kb   = (ushort_t*)p;
        float*    ACC  = (float*)p;    p += 4 * perB * Cb;   // ACC overlays Kb
        ushort_t* Vtb  = (ushort_t*)p; p += 4 * perB * Cb;

        dim3 gq  (DIMV / 256, Cb * (SEQ / 256), 1);           // (3, 64)
        dim3 gkv (2 * DIMV / 256, 2 * Cb * (SEQ / 256), 1);   // (6, 128)
        const int gcv = (int)((long long)Cb * perB / 1024);

        // 1) projections: Q from xC; fused K|V GEMM from stacked xA|xB
        f32_to_bf16<<<gcv, 256, 0, stream>>>(xC + off, xCb);
        gemm_bf16_nt_256<<<gq, 512, 0, stream>>>(xCb, Wqb, bq, nullptr, Qb, nullptr,
            DIMV, DIMV, DIMV, DIMV, 1.f, 1, 0, 0, 0, 0);
        f32_to_bf16<<<gcv, 256, 0, stream>>>(xA + off, xABb);
        f32_to_bf16<<<gcv, 256, 0, stream>>>(xB + off, xABb + (long long)Cb * perB);
        gemm_bf16_nt_256<<<gkv, 512, 0, stream>>>(xABb, Wkvb, bk, bv, Kb, Vtb,
            DIMV, DIMV, DIMV, DIMV, 1.f, 4, 0, 0, 0, Cb);

        // 2) branch-fused attention, SC batches per sub-pass
        for (int s0 = 0; s0 < Cb; s0 += SC) {
            const int sc = (s0 + SC <= Cb) ? SC : (Cb - s0);
            dim3 gsc(2 * SEQ / 256, SEQ / 256, sc);           // (8, 4, sc)
            dim3 gpv(DIMV / 128, SEQ / 128, sc);              // 128^2 kernel

            gemm_bf16_nt_256<<<gsc, 512, 0, stream>>>(
                Qb + (long long)s0 * perB, Kb + (long long)s0 * 2 * perB,
                nullptr, nullptr, Sf, nullptr,
                DIMV, DIMV, DIMV, 2 * SEQ, scale, 0, perB, 2 * perB, 2 * perP, 0);

            softmax2_inplace<<<sc * SEQ, 256, 0, stream>>>(Sf);

            gemm_bf16_nt<<<gpv, 256, 0, stream>>>(
                (const ushort_t*)Sf, Vtb + (long long)s0 * 2 * perB,
                nullptr, ACC + (long long)s0 * perB,
                2 * SEQ, 4 * SEQ, 2 * SEQ, DIMV, 1.f, 4 * perP, 2 * perB, perB);
        }

        // 3) h = LN(ACC + xC) -> bf16, into Qb (Q is dead now)
        add_layernorm<<<Cb * SEQ, 256, 0, stream>>>(ACC, xC + off, gamma, beta, Qb);

        // 4) out = h @ Wfc^T + bfc (f32 out)
        gemm_bf16_nt_256<<<gq, 512, 0, stream>>>(Qb, Wfcb, bfc, nullptr, out + off, nullptr,
            DIMV, DIMV, DIMV, DIMV, 1.f, 0, 0, 0, 0, 0);
    }
}

// Round 7
// 636.676 us; speedup vs baseline: 1.1510x; 1.0007x over previous
//
#include <hip/hip_runtime.h>

#define DIMV 768
#define BATCH 16
#define SEQ 1024
#define LN_EPS 1e-5f

typedef __attribute__((ext_vector_type(8))) short bf16x8;   // 8 bf16 = 4 VGPRs
typedef __attribute__((ext_vector_type(4))) float f32x4;
typedef unsigned short ushort_t;

__device__ __forceinline__ unsigned short f2bf(float f) {
    unsigned u = __float_as_uint(f);
    u = (u + 0x7FFFu + ((u >> 16) & 1u)) >> 16;
    return (unsigned short)u;
}

// ---------------------------------------------------------------------------
// Verified building blocks (rounds 0-6):
//  - LDS chunk swizzle q ^ ((r>>1)&3) on global SOURCE + frag-read XOR
//    (SQ_LDS_BANK_CONFLICT 9.4M -> 0).
//  - XCD swizzles: Z>1 -> XCD == batch (mod 8); Z==1 -> chunked contiguous
//    y-range per XCD (FETCH -> ~compulsory).
//  - Branch-fused attention (score N=2048 / dual softmax / PV K=2048).
//  - Lifetime overlays -> single chunk Cb=16.
//
// Pipeline-depth history:
//  - 128^2: ring-3 depth-1, 3 blocks/CU = 466 TF; ring-4 depth-2 REFUTED
//    (round 4: 3->2 blocks/CU, occupancy loss > latency gain).
//  - 256^2 ring-3 depth-1 (round 6): only +6.6% -- 1 block/CU, all 8 waves
//    stall together on vmcnt each iter (~4900 cyc wall vs ~620 cyc MFMA).
//  - THIS ROUND: at 256^2, ring-4 (128 KB) still fits 1 block/CU -> depth-2
//    is free of occupancy cost; loads get 2 compute-periods of cover.
// ---------------------------------------------------------------------------

// ---------------------------------------------------------------------------
// 256x256 tile GEMM: 512 threads = 8 waves (2 m-halves x 4 n-quarters),
// per-wave 128x64 output = acc[8][4] f32x4. BK=32, ring-4 LDS (128 KB),
// DEPTH-2 prefetch, counted vmcnt(8), setprio around MFMA cluster.
// Ring-4 safety: slot (k+2)&3 was last read at iter k-2; those reads precede
// that wave's barrier(k-1); the iter-k issue follows barrier(k-1). Tail
// iters issue clamped dummy loads (last tile, L2-hot, never read) so the
// vmcnt count stays uniform.
// mode: 0 = f32 out; 1 = bf16 out;
//       4 = fused KV epilogue, branch-stacked attention operands:
//           bh = m>>10, half = bh>=CbArg, b = bh - half*CbArg
//           n < 768 : K  -> Cout [b][half*1024 + s][n]       (bf16)
//           n >= 768: V^T-> Cout2[b][n-768][half*1024 + s]   (bf16)
// ---------------------------------------------------------------------------
__global__ __launch_bounds__(512, 2) void gemm_bf16_nt_256(
    const ushort_t* __restrict__ A, const ushort_t* __restrict__ B,
    const float* __restrict__ bias, const float* __restrict__ bias2,
    void* __restrict__ Cout, void* __restrict__ Cout2,
    int K, int lda, int ldb, int ldc, float scale, int mode,
    long long sAz, long long sBz, long long sCz, int CbArg)
{
    int bx = blockIdx.x, by = blockIdx.y, bz = blockIdx.z;
    {
        const unsigned Z  = gridDim.z;
        const unsigned nx = gridDim.x, ny = gridDim.y;
        if (Z > 1) {
            const unsigned nxy = nx * ny;
            const unsigned lid = ((unsigned)bz * ny + (unsigned)by) * nx + (unsigned)bx;
            unsigned r;
            if ((Z & 7u) == 0u) {
                const unsigned c  = lid & 7u;
                const unsigned rp = lid >> 3;
                bz = (int)(c + 8u * (rp / nxy));
                r  = rp % nxy;
            } else {
                bz = (int)(lid % Z);
                r  = lid / Z;
            }
            bx = (int)(r % nx);
            by = (int)(r / nx);
        } else {
            const unsigned nwg = nx * ny;
            if ((nwg & 7u) == 0u) {
                const unsigned lid = (unsigned)by * nx + (unsigned)bx;
                const unsigned nl  = (lid & 7u) * (nwg >> 3) + (lid >> 3);
                bx = (int)(nl % nx);
                by = (int)(nl / nx);
            }
        }
    }

    A += (long long)bz * sAz;
    B += (long long)bz * sBz;
    float*    Cf  = (float*)Cout    + ((mode == 0) ? (long long)bz * sCz : 0);
    ushort_t* Ch  = (ushort_t*)Cout + ((mode == 1) ? (long long)bz * sCz : 0);
    ushort_t* Ch2 = (ushort_t*)Cout2;

    __shared__ ushort_t As[4][256 * 32];   // 4 x 16 KB
    __shared__ ushort_t Bs[4][256 * 32];   // 4 x 16 KB  (128 KB total)

    const int t    = threadIdx.x;       // 0..511
    const int wave = t >> 6;            // 0..7
    const int lane = t & 63;
    const int quad = lane >> 4;         // 0..3
    const int lr   = lane & 15;         // 0..15
    const int wy   = wave >> 2;         // 0/1: m-half (128 rows)
    const int wx   = wave & 3;          // 0..3: n-quarter (64 cols)

    const int m0 = by * 256;
    const int n0 = bx * 256;

    const ushort_t* Abase = A + (long long)m0 * lda;
    const ushort_t* Bbase = B + (long long)n0 * ldb;

    auto issue = [&](int k0, int slot) {
        #pragma unroll
        for (int i = 0; i < 2; ++i) {
            const int idx = t + 512 * i;          // 0..1023: 256 rows x 4 chunks
            const int r   = idx >> 2;
            const int q   = idx & 3;              // LDS chunk slot
            const int c   = (q ^ ((r >> 1) & 3)) * 8;  // swizzled global chunk
            __builtin_amdgcn_global_load_lds(
                (const __attribute__((address_space(1))) unsigned int*)(Abase + (long long)r * lda + k0 + c),
                (__attribute__((address_space(3))) unsigned int*)&As[slot][idx * 8], 16, 0, 0);
            __builtin_amdgcn_global_load_lds(
                (const __attribute__((address_space(1))) unsigned int*)(Bbase + (long long)r * ldb + k0 + c),
                (__attribute__((address_space(3))) unsigned int*)&Bs[slot][idx * 8], 16, 0, 0);
        }
    };

    int offA[8], offB[4];
    #pragma unroll
    for (int i = 0; i < 8; ++i) {
        const int rowA = wy * 128 + i * 16 + lr;
        offA[i] = rowA * 32 + ((quad ^ ((rowA >> 1) & 3)) * 8);
    }
    #pragma unroll
    for (int j = 0; j < 4; ++j) {
        const int rowB = wx * 64 + j * 16 + lr;
        offB[j] = rowB * 32 + ((quad ^ ((rowB >> 1) & 3)) * 8);
    }

    f32x4 acc[8][4] = {};

    const int NK = K >> 5;                 // >= 24 for all callers
    issue(0, 0);
    issue(32, 1);
    for (int ki = 0; ki < NK; ++ki) {
        const int k2 = (ki + 2 < NK) ? (ki + 2) << 5 : (NK - 1) << 5;  // clamped dummy
        issue(k2, (ki + 2) & 3);
        asm volatile("s_waitcnt vmcnt(8)" ::: "memory");   // tile-k done; k+1,k+2 in flight
        asm volatile("s_barrier" ::: "memory");            // no vmcnt(0) drain

        const ushort_t* as = &As[ki & 3][0];
        const ushort_t* bs = &Bs[ki & 3][0];
        bf16x8 af[8], bfr[4];
        #pragma unroll
        for (int i = 0; i < 8; ++i) af[i]  = *(const bf16x8*)&as[offA[i]];
        #pragma unroll
        for (int j = 0; j < 4; ++j) bfr[j] = *(const bf16x8*)&bs[offB[j]];

        __builtin_amdgcn_s_setprio(1);
        #pragma unroll
        for (int i = 0; i < 8; ++i)
            #pragma unroll
            for (int j = 0; j < 4; ++j)
                acc[i][j] = __builtin_amdgcn_mfma_f32_16x16x32_bf16(
                    af[i], bfr[j], acc[i][j], 0, 0, 0);
        __builtin_amdgcn_s_setprio(0);
    }

    // epilogue: D row(m) = quad*4 + reg, col(n) = lane&15  [m89-verified]
    #pragma unroll
    for (int j = 0; j < 4; ++j) {
        const int n = n0 + wx * 64 + j * 16 + lr;
        float bv;
        if (mode == 4) bv = (n < DIMV) ? bias[n] : bias2[n - DIMV];
        else           bv = bias ? bias[n] : 0.0f;
        #pragma unroll
        for (int i = 0; i < 8; ++i) {
            #pragma unroll
            for (int r = 0; r < 4; ++r) {
                const int m = m0 + wy * 128 + i * 16 + quad * 4 + r;
                const float val = acc[i][j][r] * scale + bv;
                if (mode == 0) {
                    Cf[(long long)m * ldc + n] = val;
                } else if (mode == 1) {
                    Ch[(long long)m * ldc + n] = f2bf(val);
                } else {                      // mode 4: fused KV, branch-stacked
                    const int bh = m >> 10, s = m & 1023;
                    const int hf = (bh >= CbArg) ? 1 : 0;
                    const int b  = bh - (hf ? CbArg : 0);
                    if (n < DIMV) {
                        Ch[(long long)b * (2 * SEQ * DIMV) + (long long)(hf * SEQ + s) * DIMV + n] = f2bf(val);
                    } else {
                        Ch2[(long long)b * (2 * SEQ * DIMV) + (long long)(n - DIMV) * (2 * SEQ) + hf * SEQ + s] = f2bf(val);
                    }
                }
            }
        }
    }
}

// ---------------------------------------------------------------------------
// 128x128 tile GEMM, ring-3 depth-1 (verified rounds 0-5) — kept for PV,
// whose per-batch grid underfills the chip at 256^2 tiles. mode 0 only.
// (ring-4 depth-2 at 128^2 REFUTED round 4: occupancy 3->2 blocks/CU.)
// ---------------------------------------------------------------------------
__global__ __launch_bounds__(256) void gemm_bf16_nt(
    const ushort_t* __restrict__ A, const ushort_t* __restrict__ B,
    const float* __restrict__ bias, void* __restrict__ Cout,
    int K, int lda, int ldb, int ldc, float scale,
    long long sAz, long long sBz, long long sCz)
{
    int bx = blockIdx.x, by = blockIdx.y, bz = blockIdx.z;
    {
        const unsigned Z  = gridDim.z;
        const unsigned nx = gridDim.x, ny = gridDim.y;
        if (Z > 1) {
            const unsigned nxy = nx * ny;
            const unsigned lid = ((unsigned)bz * ny + (unsigned)by) * nx + (unsigned)bx;
            unsigned r;
            if ((Z & 7u) == 0u) {
                const unsigned c  = lid & 7u;
                const unsigned rp = lid >> 3;
                bz = (int)(c + 8u * (rp / nxy));
                r  = rp % nxy;
            } else {
                bz = (int)(lid % Z);
                r  = lid / Z;
            }
            bx = (int)(r % nx);
            by = (int)(r / nx);
        } else {
            const unsigned nwg = nx * ny;
            if ((nwg & 7u) == 0u) {
                const unsigned lid = (unsigned)by * nx + (unsigned)bx;
                const unsigned nl  = (lid & 7u) * (nwg >> 3) + (lid >> 3);
                bx = (int)(nl % nx);
                by = (int)(nl / nx);
            }
        }
    }

    A += (long long)bz * sAz;
    B += (long long)bz * sBz;
    float* Cf = (float*)Cout + (long long)bz * sCz;

    __shared__ ushort_t As[3][128 * 32];
    __shared__ ushort_t Bs[3][128 * 32];

    const int t    = threadIdx.x;
    const int wave = t >> 6;
    const int lane = t & 63;
    const int quad = lane >> 4;
    const int lr   = lane & 15;
    const int wy   = wave >> 1;
    const int wx   = wave & 1;

    const int m0 = by * 128;
    const int n0 = bx * 128;

    const ushort_t* Abase = A + (long long)m0 * lda;
    const ushort_t* Bbase = B + (long long)n0 * ldb;

    auto issue = [&](int k0, int slot) {
        #pragma unroll
        for (int i = 0; i < 2; ++i) {
            const int idx = t + 256 * i;
            const int r   = idx >> 2;
            const int q   = idx & 3;
            const int c   = (q ^ ((r >> 1) & 3)) * 8;
            __builtin_amdgcn_global_load_lds(
                (const __attribute__((address_space(1))) unsigned int*)(Abase + (long long)r * lda + k0 + c),
                (__attribute__((address_space(3))) unsigned int*)&As[slot][idx * 8], 16, 0, 0);
            __builtin_amdgcn_global_load_lds(
                (const __attribute__((address_space(1))) unsigned int*)(Bbase + (long long)r * ldb + k0 + c),
                (__attribute__((address_space(3))) unsigned int*)&Bs[slot][idx * 8], 16, 0, 0);
        }
    };

    int offA[4], offB[4];
    #pragma unroll
    for (int i = 0; i < 4; ++i) {
        const int rowA = wy * 64 + i * 16 + lr;
        offA[i] = rowA * 32 + ((quad ^ ((rowA >> 1) & 3)) * 8);
        const int rowB = wx * 64 + i * 16 + lr;
        offB[i] = rowB * 32 + ((quad ^ ((rowB >> 1) & 3)) * 8);
    }

    f32x4 acc[4][4] = {};

    const int NK = K >> 5;
    issue(0, 0);
    int cur = 0, nxt = 1;
    for (int ki = 0; ki < NK; ++ki) {
        const int kn = (ki + 1 < NK) ? (ki + 1) << 5 : 0;
        issue(kn, nxt);
        asm volatile("s_waitcnt vmcnt(4)" ::: "memory");
        asm volatile("s_barrier" ::: "memory");

        const ushort_t* as = &As[cur][0];
        const ushort_t* bs = &Bs[cur][0];
        bf16x8 af[4], bfr[4];
        #pragma unroll
        for (int i = 0; i < 4; ++i) af[i]  = *(const bf16x8*)&as[offA[i]];
        #pragma unroll
        for (int j = 0; j < 4; ++j) bfr[j] = *(const bf16x8*)&bs[offB[j]];

        #pragma unroll
        for (int i = 0; i < 4; ++i)
            #pragma unroll
            for (int j = 0; j < 4; ++j)
                acc[i][j] = __builtin_amdgcn_mfma_f32_16x16x32_bf16(
                    af[i], bfr[j], acc[i][j], 0, 0, 0);

        cur = nxt;
        nxt = (nxt == 2) ? 0 : nxt + 1;
    }

    #pragma unroll
    for (int j = 0; j < 4; ++j) {
        const int n = n0 + wx * 64 + j * 16 + lr;
        const float bv = bias ? bias[n] : 0.0f;
        #pragma unroll
        for (int i = 0; i < 4; ++i) {
            #pragma unroll
            for (int r = 0; r < 4; ++r) {
                const int m = m0 + wy * 64 + i * 16 + quad * 4 + r;
                Cf[(long long)m * ldc + n] = acc[i][j][r] * scale + bv;
            }
        }
    }
}

// ---------------------------------------------------------------------------
// f32 -> bf16 conversion, 4 elems/thread, count divisible by 1024
// ---------------------------------------------------------------------------
__global__ __launch_bounds__(256) void f32_to_bf16(
    const float* __restrict__ in, ushort_t* __restrict__ out)
{
    const long long i = ((long long)blockIdx.x * 256 + threadIdx.x) * 4;
    float4 v = *reinterpret_cast<const float4*>(in + i);
    ushort4 o;
    o.x = f2bf(v.x); o.y = f2bf(v.y); o.z = f2bf(v.z); o.w = f2bf(v.w);
    *reinterpret_cast<ushort4*>(out + i) = o;
}

// ---------------------------------------------------------------------------
// Dual in-place row softmax over a [2048] f32 row (two independent 1024
// halves). Row overwritten with 2048 contiguous bf16 probs. [verified r4]
// ---------------------------------------------------------------------------
__global__ __launch_bounds__(256) void softmax2_inplace(float* __restrict__ S)
{
    float* s = S + (long long)blockIdx.x * (2 * SEQ);
    const int t  = threadIdx.x;
    const int hf = t >> 7;
    const int tt = t & 127;
    const int base = hf * SEQ + tt * 8;
    __shared__ float red[256];

    float4 v0 = *reinterpret_cast<const float4*>(&s[base]);
    float4 v1 = *reinterpret_cast<const float4*>(&s[base + 4]);
    float mx = fmaxf(fmaxf(fmaxf(v0.x, v0.y), fmaxf(v0.z, v0.w)),
                     fmaxf(fmaxf(v1.x, v1.y), fmaxf(v1.z, v1.w)));
    red[t] = mx;
    __syncthreads();
    for (int st = 64; st > 0; st >>= 1) {
        if (tt < st) red[t] = fmaxf(red[t], red[t + st]);
        __syncthreads();
    }
    mx = red[hf << 7];
    __syncthreads();

    v0.x = __expf(v0.x - mx); v0.y = __expf(v0.y - mx);
    v0.z = __expf(v0.z - mx); v0.w = __expf(v0.w - mx);
    v1.x = __expf(v1.x - mx); v1.y = __expf(v1.y - mx);
    v1.z = __expf(v1.z - mx); v1.w = __expf(v1.w - mx);
    red[t] = (v0.x + v0.y + v0.z + v0.w) + (v1.x + v1.y + v1.z + v1.w);
    __syncthreads();
    for (int st = 64; st > 0; st >>= 1) {
        if (tt < st) red[t] += red[t + st];
        __syncthreads();
    }
    const float inv = 1.0f / red[hf << 7];

    ushort4 o0, o1;
    o0.x = f2bf(v0.x * inv); o0.y = f2bf(v0.y * inv);
    o0.z = f2bf(v0.z * inv); o0.w = f2bf(v0.w * inv);
    o1.x = f2bf(v1.x * inv); o1.y = f2bf(v1.y * inv);
    o1.z = f2bf(v1.z * inv); o1.w = f2bf(v1.w * inv);
    *reinterpret_cast<ushort4*>((ushort_t*)s + base)     = o0;
    *reinterpret_cast<ushort4*>((ushort_t*)s + base + 4) = o1;
}

// ---------------------------------------------------------------------------
// h = LayerNorm(ACC + xC) * gamma + beta -> bf16. One block per row (768).
// ---------------------------------------------------------------------------
__global__ __launch_bounds__(256) void add_layernorm(
    const float* __restrict__ ACC, const float* __restrict__ xC,
    const float* __restrict__ gamma, const float* __restrict__ beta,
    ushort_t* __restrict__ H)
{
    const long long row = blockIdx.x;
    const float* a = ACC + row * DIMV;
    const float* x = xC  + row * DIMV;
    ushort_t*    h = H   + row * DIMV;
    const int t = threadIdx.x;

    __shared__ float r1[256];
    __shared__ float r2[256];

    float vals[3];
    float s = 0.f, ss = 0.f;
    #pragma unroll
    for (int i = 0; i < 3; ++i) {
        const int j = t + i * 256;
        float v = a[j] + x[j];
        vals[i] = v;
        s += v; ss += v * v;
    }
    r1[t] = s; r2[t] = ss;
    __syncthreads();
    for (int st = 128; st > 0; st >>= 1) {
        if (t < st) { r1[t] += r1[t + st]; r2[t] += r2[t + st]; }
        __syncthreads();
    }
    const float mu  = r1[0] * (1.0f / DIMV);
    const float var = r2[0] * (1.0f / DIMV) - mu * mu;
    const float inv = rsqrtf(var + LN_EPS);

    #pragma unroll
    for (int i = 0; i < 3; ++i) {
        const int j = t + i * 256;
        h[j] = f2bf((vals[i] - mu) * inv * gamma[j] + beta[j]);
    }
}

// ---------------------------------------------------------------------------
// Launch. Persistent: bf16 weights Wqb | Wkvb (=[Wk;Wv]) | Wfcb (4.72 MB).
// Lifetime-overlay layout per chunk [verified round 5, single chunk Cb=16]:
//   Region S: xCb / xABb / Sf (sequential lifetimes)
//   Qb; KbACC (Kb overlaid by ACC per sub-pass); Vtb
// Attention branch-fused per SC-batch sub-pass:
//   score (N=2048) -> dual softmax -> PV (K=2048, no RMW).
// 256^2 depth-2 GEMM for Q/KV/score/fc; 128^2 ring-3 for PV.
// ---------------------------------------------------------------------------
extern "C" void kernel_launch(void* const* d_in, const int* in_sizes, int n_in,
                              void* d_out, int out_size, void* d_ws, size_t ws_size,
                              hipStream_t stream)
{
    const float* xA    = (const float*)d_in[0];
    const float* xB    = (const float*)d_in[1];
    const float* xC    = (const float*)d_in[2];
    const float* Wq    = (const float*)d_in[3];
    const float* bq    = (const float*)d_in[4];
    const float* Wk    = (const float*)d_in[5];
    const float* bk    = (const float*)d_in[6];
    const float* Wv    = (const float*)d_in[7];
    const float* bv    = (const float*)d_in[8];
    const float* gamma = (const float*)d_in[9];
    const float* beta  = (const float*)d_in[10];
    const float* Wfc   = (const float*)d_in[11];
    const float* bfc   = (const float*)d_in[12];
    float* out = (float*)d_out;

    const long long eW   = (long long)DIMV * DIMV;   // 589,824
    const long long perB = (long long)SEQ * DIMV;    // 786,432 elems
    const long long perP = (long long)SEQ * SEQ;     // 1,048,576 elems

    const long long wBytes = 4 * eW * 2;             // 4.72 MB

    auto needBytes = [&](long long cb, long long sc) {
        const long long s = 8 * perP * sc;           // Sf f32 bytes
        const long long x = 4 * perB * cb;           // xABb bf16 bytes
        return (s > x ? s : x) + 10 * perB * cb;     // + Qb + KbACC + Vtb
    };

    int CbFit = 1;
    for (int c = BATCH; c >= 1; --c) {
        const long long sc = c < 8 ? c : 8;
        if (wBytes + needBytes(c, sc) <= (long long)ws_size) { CbFit = c; break; }
    }
    const int nChunks = (BATCH + CbFit - 1) / CbFit;
    const int CbStd   = (BATCH + nChunks - 1) / nChunks;

    char* cur = (char*)d_ws;
    ushort_t* Wqb  = (ushort_t*)cur; cur += eW * 2;
    ushort_t* Wkvb = (ushort_t*)cur; cur += 2 * eW * 2;    // [Wk; Wv] 1536x768
    ushort_t* Wfcb = (ushort_t*)cur; cur += eW * 2;
    char* chunkBase = cur;

    const float scale = 0.03608439182435161f;  // 1/sqrt(768)

    f32_to_bf16<<<(int)(eW / 1024), 256, 0, stream>>>(Wq,  Wqb);
    f32_to_bf16<<<(int)(eW / 1024), 256, 0, stream>>>(Wk,  Wkvb);
    f32_to_bf16<<<(int)(eW / 1024), 256, 0, stream>>>(Wv,  Wkvb + eW);
    f32_to_bf16<<<(int)(eW / 1024), 256, 0, stream>>>(Wfc, Wfcb);

    for (int b0 = 0; b0 < BATCH; b0 += CbStd) {
        const int Cb = (b0 + CbStd <= BATCH) ? CbStd : (BATCH - b0);
        const long long off = (long long)b0 * perB;

        int SC = Cb;
        while (SC > 1 && wBytes + needBytes(Cb, SC) > (long long)ws_size) --SC;

        const long long Sbytes =
            (8 * perP * (long long)SC > 4 * perB * (long long)Cb)
                ? 8 * perP * (long long)SC : 4 * perB * (long long)Cb;

        char* p = chunkBase;
        ushort_t* xCb  = (ushort_t*)p;                 // overlay 1 in region S
        ushort_t* xABb = (ushort_t*)p;                 // overlay 2 in region S
        float*    Sf   = (float*)p;    p += Sbytes;    // overlay 3 in region S
        ushort_t* Qb   = (ushort_t*)p; p += 2 * perB * Cb;
        ushort_t* Kb   = (ushort_t*)p;
        float*    ACC  = (float*)p;    p += 4 * perB * Cb;   // ACC overlays Kb
        ushort_t* Vtb  = (ushort_t*)p; p += 4 * perB * Cb;

        dim3 gq  (DIMV / 256, Cb * (SEQ / 256), 1);           // (3, 64)
        dim3 gkv (2 * DIMV / 256, 2 * Cb * (SEQ / 256), 1);   // (6, 128)
        const int gcv = (int)((long long)Cb * perB / 1024);

        // 1) projections: Q from xC; fused K|V GEMM from stacked xA|xB
        f32_to_bf16<<<gcv, 256, 0, stream>>>(xC + off, xCb);
        gemm_bf16_nt_256<<<gq, 512, 0, stream>>>(xCb, Wqb, bq, nullptr, Qb, nullptr,
            DIMV, DIMV, DIMV, DIMV, 1.f, 1, 0, 0, 0, 0);
        f32_to_bf16<<<gcv, 256, 0, stream>>>(xA + off, xABb);
        f32_to_bf16<<<gcv, 256, 0, stream>>>(xB + off, xABb + (long long)Cb * perB);
        gemm_bf16_nt_256<<<gkv, 512, 0, stream>>>(xABb, Wkvb, bk, bv, Kb, Vtb,
            DIMV, DIMV, DIMV, DIMV, 1.f, 4, 0, 0, 0, Cb);

        // 2) branch-fused attention, SC batches per sub-pass
        for (int s0 = 0; s0 < Cb; s0 += SC) {
            const int sc = (s0 + SC <= Cb) ? SC : (Cb - s0);
            dim3 gsc(2 * SEQ / 256, SEQ / 256, sc);           // (8, 4, sc)
            dim3 gpv(DIMV / 128, SEQ / 128, sc);              // 128^2 kernel

            gemm_bf16_nt_256<<<gsc, 512, 0, stream>>>(
                Qb + (long long)s0 * perB, Kb + (long long)s0 * 2 * perB,
                nullptr, nullptr, Sf, nullptr,
                DIMV, DIMV, DIMV, 2 * SEQ, scale, 0, perB, 2 * perB, 2 * perP, 0);

            softmax2_inplace<<<sc * SEQ, 256, 0, stream>>>(Sf);

            gemm_bf16_nt<<<gpv, 256, 0, stream>>>(
                (const ushort_t*)Sf, Vtb + (long long)s0 * 2 * perB,
                nullptr, ACC + (long long)s0 * perB,
                2 * SEQ, 4 * SEQ, 2 * SEQ, DIMV, 1.f, 4 * perP, 2 * perB, perB);
        }

        // 3) h = LN(ACC + xC) -> bf16, into Qb (Q is dead now)
        add_layernorm<<<Cb * SEQ, 256, 0, stream>>>(ACC, xC + off, gamma, beta, Qb);

        // 4) out = h @ Wfc^T + bfc (f32 out)
        gemm_bf16_nt_256<<<gq, 512, 0, stream>>>(Qb, Wfcb, bfc, nullptr, out + off, nullptr,
            DIMV, DIMV, DIMV, DIMV, 1.f, 0, 0, 0, 0, 0);
    }
}